// Round 8
// baseline (803.451 us; speedup 1.0000x reference)
//
#include <hip/hip_runtime.h>

// SparseMoE: B=2,S=2048 -> N=4096 tokens, D=1024, HIDDEN=2816, 8 experts, top-2, cap=1024
// Round 8: round-7 minus the B-load stall. B reg-staging deepened to 2 tiles
// (named ping-pong rbA/rbB, BLOAD(i+3) at iter i -> ~2 iterations of latency slack).
// Queue invariant per iter: issue [BLOAD x8 @start, ASTAGE x4 @mid]; single end
// waitv<12> completes A(i+1) (pre-barrier, cross-wave DMA) and B(i+2) (next BWRITE).
// No iter-start wait. Tail: N = 8*[i+3<KTS] + 4*[i+2<KTS].

#define D_MODEL 1024
#define HIDDEN 2816
#define N_TOK 4096
#define CAP 1024

typedef __attribute__((ext_vector_type(8))) short short8;
typedef __attribute__((ext_vector_type(4))) float f32x4;

__device__ __forceinline__ unsigned short f2bf(float f) {
  unsigned int u = __float_as_uint(f);
  u += 0x7fffu + ((u >> 16) & 1u);   // RNE
  return (unsigned short)(u >> 16);
}
__device__ __forceinline__ float bf2f(unsigned short h) {
  return __uint_as_float(((unsigned int)h) << 16);
}
__device__ __forceinline__ unsigned cvtpk(float lo, float hi) {
  unsigned r;
  asm("v_cvt_pk_bf16_f32 %0, %1, %2" : "=v"(r) : "v"(lo), "v"(hi));
  return r;
}

template <int Ncnt> __device__ __forceinline__ void waitv() {
  if constexpr (Ncnt == 16)      asm volatile("s_waitcnt vmcnt(16)" ::: "memory");
  else if constexpr (Ncnt == 12) asm volatile("s_waitcnt vmcnt(12)" ::: "memory");
  else if constexpr (Ncnt == 8)  asm volatile("s_waitcnt vmcnt(8)" ::: "memory");
  else if constexpr (Ncnt == 4)  asm volatile("s_waitcnt vmcnt(4)" ::: "memory");
  else                           asm volatile("s_waitcnt vmcnt(0)" ::: "memory");
}

// ---------------- router: logits, noisy top-2, gates ----------------
__global__ void router_kernel(const float* __restrict__ x, const float* __restrict__ noise,
                              const float* __restrict__ rw, const float* __restrict__ rb,
                              const float* __restrict__ nw, const float* __restrict__ nb,
                              int* __restrict__ topi, float* __restrict__ gall,
                              int* __restrict__ slot) {
  int wid = threadIdx.x >> 6;
  int lane = threadIdx.x & 63;
  int t = blockIdx.x * 4 + wid;
  if (t >= N_TOK) return;
  const float* xr = x + (size_t)t * D_MODEL;
  double accL[8] = {0,0,0,0,0,0,0,0};
  double accN[8] = {0,0,0,0,0,0,0,0};
  for (int i = 0; i < 4; ++i) {
    int kb = (i * 64 + lane) * 4;
    float4 xv = *(const float4*)(xr + kb);
#pragma unroll
    for (int e = 0; e < 8; ++e) {
      float4 wv = *(const float4*)(rw + e * D_MODEL + kb);
      accL[e] += (double)xv.x * wv.x + (double)xv.y * wv.y + (double)xv.z * wv.z + (double)xv.w * wv.w;
      float4 nv = *(const float4*)(nw + e * D_MODEL + kb);
      accN[e] += (double)xv.x * nv.x + (double)xv.y * nv.y + (double)xv.z * nv.z + (double)xv.w * nv.w;
    }
  }
#pragma unroll
  for (int e = 0; e < 8; ++e) {
    for (int s = 32; s > 0; s >>= 1) {
      accL[e] += __shfl_xor(accL[e], s);
      accN[e] += __shfl_xor(accN[e], s);
    }
  }
  if (lane == 0) {
    double noisy[8];
#pragma unroll
    for (int e = 0; e < 8; ++e) {
      double lg = accL[e] + (double)rb[e];
      double nl = accN[e] + (double)nb[e];
      double sp = (nl > 0.0 ? nl : 0.0) + log1p(exp(-fabs(nl)));  // softplus, stable
      noisy[e] = lg + (double)noise[t * 8 + e] * sp;
    }
    int i0 = 0;
    for (int e = 1; e < 8; ++e) if (noisy[e] > noisy[i0]) i0 = e;
    int i1 = -1;
    for (int e = 0; e < 8; ++e) { if (e == i0) continue; if (i1 < 0 || noisy[e] > noisy[i1]) i1 = e; }
    double g0 = 1.0 / (1.0 + exp(noisy[i1] - noisy[i0]));
    topi[t * 2] = i0; topi[t * 2 + 1] = i1;
    gall[t * 2] = (float)g0; gall[t * 2 + 1] = (float)(1.0 - g0);
    slot[t * 2] = -1; slot[t * 2 + 1] = -1;
  }
}

// ---------------- per-expert capacity scan (token-index order) ----------------
__global__ void scan_kernel(const int* __restrict__ topi,
                            int* __restrict__ slot, int* __restrict__ tok_list) {
  int e = blockIdx.x;
  int tid = threadIdx.x;
  int lane = tid & 63, wid = tid >> 6;
  __shared__ int wsum[16];
  __shared__ int base_s;
  tok_list[e * CAP + tid] = -1;
  if (tid == 0) base_s = 0;
  __syncthreads();
  for (int chunk = 0; chunk < N_TOK / 1024; ++chunk) {
    int t = chunk * 1024 + tid;
    int i0 = topi[t * 2], i1 = topi[t * 2 + 1];
    bool m = (i0 == e) || (i1 == e);
    unsigned long long mask = __ballot(m);
    int excl = __popcll(mask & ((1ull << lane) - 1ull));
    if (lane == 0) wsum[wid] = __popcll(mask);
    __syncthreads();
    int base = base_s;
    int woff = 0;
    for (int w = 0; w < wid; ++w) woff += wsum[w];
    int pos = base + woff + excl;
    if (m && pos < CAP) {
      tok_list[e * CAP + pos] = t;
      if (i0 == e) slot[t * 2] = pos; else slot[t * 2 + 1] = pos;
    }
    __syncthreads();
    if (tid == 0) {
      int s = 0;
      for (int w = 0; w < 16; ++w) s += wsum[w];
      base_s = base + s;
    }
    __syncthreads();
  }
}

// ---------------- gather x rows into per-expert bf16 buffers ----------------
__global__ void gather_kernel(const float* __restrict__ x, const int* __restrict__ tok_list,
                              unsigned short* __restrict__ xb) {
  int row = blockIdx.x;
  int tok = tok_list[row];
  unsigned short* dst = xb + (size_t)row * D_MODEL + threadIdx.x * 4;
  if (tok < 0) {
    *(ushort4*)dst = make_ushort4(0, 0, 0, 0);
  } else {
    float4 v = *(const float4*)(x + (size_t)tok * D_MODEL + threadIdx.x * 4);
    *(ushort4*)dst = make_ushort4(f2bf(v.x), f2bf(v.y), f2bf(v.z), f2bf(v.w));
  }
}

// ============ grouped GEMM, f32 weights converted in-kernel (2-deep B prefetch) ============
// BM=256, 8 waves (2M x 4N), 2 bf16 B-panels of 128 cols in LDS, A via gload_lds.
// B path: 8x global_load_dwordx4 (f32, 2 tiles ahead) -> v_cvt_pk_bf16_f32 -> swizzled
// ds_write_b128. MODE 1 (FUSE): silu(acc0)*acc1 -> bf16 h. MODE 2 (PART): BNCOL=256,
// split-K SK=2, ungated f32 partial stores.
template <int NOUT, int K, int MODE>
__global__ __launch_bounds__(512, 1)
void gemm_moe(const unsigned short* __restrict__ Ab, const float* __restrict__ W0,
              const float* __restrict__ W1, void* __restrict__ OUT) {
  constexpr int ABYTES = 32768;
  constexpr int BUFSZ = ABYTES + 32768;
  constexpr int KT = K / 64;
  constexpr int SK = (MODE == 2) ? 2 : 1;
  constexpr int KTS = KT / SK;                 // 16 or 22 (even)
  constexpr int BNCOL = (MODE == 2) ? 256 : 128;
  constexpr int NBN = NOUT / BNCOL;
  constexpr int NWG = 8 * 4 * NBN * SK;

  __shared__ char smem[2 * BUFSZ];

  // bijective XCD swizzle + decode (NWG % 8 == 0)
  int lid = blockIdx.x;
  int swz = (lid & 7) * (NWG / 8) + (lid >> 3);
  constexpr int PERE = 4 * NBN * SK;
  int e = swz / PERE;
  int r = swz - e * PERE;
  int bm = r / (NBN * SK);
  int r2 = r - bm * (NBN * SK);
  int bn = r2 / SK;
  int sk = r2 - bn * SK;
  int kt0 = sk * KTS;

  const unsigned short* A = Ab + (size_t)e * CAP * K;
  int tid = threadIdx.x, lane = tid & 63, wid = tid >> 6;
  int wr = wid >> 2, wc = wid & 3;
  int lane15 = lane & 15, lhi = lane >> 4, l7 = lane & 7;

  // A stage: pre-swizzled global source (16B slot ^= row&7), linear LDS dest
  int lrow = lane >> 3;
  int lcol = ((lane & 7) ^ lrow) * 8;
  const unsigned short* Abase = A + (size_t)(bm * 256 + lrow) * K + lcol;

  auto ASTAGE = [&](int ktile, int buf) {
#pragma unroll
    for (int i = 0; i < 4; ++i) {
      int c = wid * 4 + i;
      const unsigned short* g = Abase + (size_t)(c * 8) * K + ktile * 64;
      __builtin_amdgcn_global_load_lds((const __attribute__((address_space(1))) void*)g,
                                       (__attribute__((address_space(3))) void*)(smem + buf * BUFSZ + c * 1024), 16, 0, 0);
    }
  };

  // B slots: L = i*512 + tid -> panel (i>>1, compile-time), row p, 8-elem k-slot ks
  const float* wptr[4];
  int woff[4];
#pragma unroll
  for (int i = 0; i < 4; ++i) {
    int L = i * 512 + tid;
    int p = (L >> 3) & 127;
    int ks = L & 7;
    const float* Wb = (i >> 1) ? W1 : W0;
    wptr[i] = Wb + (size_t)e * NOUT * K + (size_t)(bn * BNCOL + p) * K + ks * 8;
    woff[i] = ABYTES + (i >> 1) * 16384 + p * 128 + ((ks ^ (p & 7)) * 16);
  }

  float4 rbA[4][2], rbB[4][2];
  auto BLOAD = [&](int ktile, float4 (&rb)[4][2]) {
#pragma unroll
    for (int i = 0; i < 4; ++i) {
      const float* s = wptr[i] + (size_t)ktile * 64;
      rb[i][0] = *(const float4*)(s);
      rb[i][1] = *(const float4*)(s + 4);
    }
  };
  auto BWRITE = [&](char* lb, const float4 (&rb)[4][2]) {
#pragma unroll
    for (int i = 0; i < 4; ++i) {
      uint4 v;
      v.x = cvtpk(rb[i][0].x, rb[i][0].y);
      v.y = cvtpk(rb[i][0].z, rb[i][0].w);
      v.z = cvtpk(rb[i][1].x, rb[i][1].y);
      v.w = cvtpk(rb[i][1].z, rb[i][1].w);
      *(uint4*)(lb + woff[i]) = v;
    }
  };

  // swizzled ds_read slot offsets (same involution as write side)
  int sw0 = ((0 + lhi) ^ l7) * 16;
  int sw1 = ((4 + lhi) ^ l7) * 16;

  f32x4 acc[8][2][2] = {};

  // ---- prologue: queue = [B0x8, B1x8, A0x4, A1x4] ----
  BLOAD(kt0, rbA);
  BLOAD(kt0 + 1, rbB);
  __builtin_amdgcn_sched_barrier(0);
  ASTAGE(kt0, 0);
  ASTAGE(kt0 + 1, 1);
  __builtin_amdgcn_sched_barrier(0);
  waitv<16>();                    // B0 regs done
  BWRITE(smem, rbA);
  BLOAD(kt0 + 2, rbA);            // queue [B1x8, A0x4, A1x4, B2x8]
  __builtin_amdgcn_sched_barrier(0);
  waitv<12>();                    // A0 done (completes B1 too); leaves [A1x4, B2x8]
  asm volatile("s_waitcnt lgkmcnt(0)" ::: "memory");
  __builtin_amdgcn_sched_barrier(0);
  __builtin_amdgcn_s_barrier();
  __builtin_amdgcn_sched_barrier(0);

  // ---- K loop. Invariant at iter i start: outstanding = [B(i+2)x8, A(i+1)x4];
  //      B(i+1) regs complete (prev end waitv<12>).
  auto ITER = [&](int ktl, float4 (&rbW)[4][2]) {
    char* cb = smem + (ktl & 1) * BUFSZ;
    char* nbuf = smem + ((ktl + 1) & 1) * BUFSZ;
    if (ktl + 1 < KTS) BWRITE(nbuf, rbW);            // B(ktl+1), regs ready
    if (ktl + 3 < KTS) BLOAD(kt0 + ktl + 3, rbW);    // reuse same reg buffer
    __builtin_amdgcn_sched_barrier(0);
    short8 a0[8], b0[2][2], a1[8], b1[2][2];
#pragma unroll
    for (int w = 0; w < 2; ++w)
#pragma unroll
      for (int n = 0; n < 2; ++n)
        b0[w][n] = *(const short8*)(cb + ABYTES + w * 16384 + wc * 4096 + n * 2048 + lane15 * 128 + sw0);
#pragma unroll
    for (int m = 0; m < 8; ++m)
      a0[m] = *(const short8*)(cb + wr * 16384 + m * 2048 + lane15 * 128 + sw0);
    __builtin_amdgcn_s_setprio(1);
#pragma unroll
    for (int m = 0; m < 8; ++m)
#pragma unroll
      for (int w = 0; w < 2; ++w)
#pragma unroll
        for (int n = 0; n < 2; ++n)
          acc[m][w][n] = __builtin_amdgcn_mfma_f32_16x16x32_bf16(a0[m], b0[w][n], acc[m][w][n], 0, 0, 0);
    __builtin_amdgcn_s_setprio(0);
#pragma unroll
    for (int w = 0; w < 2; ++w)
#pragma unroll
      for (int n = 0; n < 2; ++n)
        b1[w][n] = *(const short8*)(cb + ABYTES + w * 16384 + wc * 4096 + n * 2048 + lane15 * 128 + sw1);
#pragma unroll
    for (int m = 0; m < 8; ++m)
      a1[m] = *(const short8*)(cb + wr * 16384 + m * 2048 + lane15 * 128 + sw1);
    // all ds_reads of cb issued -> safe to DMA into cb's A region after barrier
    __builtin_amdgcn_sched_barrier(0);
    __builtin_amdgcn_s_barrier();
    __builtin_amdgcn_sched_barrier(0);
    if (ktl + 2 < KTS) ASTAGE(kt0 + ktl + 2, ktl & 1);
    __builtin_amdgcn_s_setprio(1);
#pragma unroll
    for (int m = 0; m < 8; ++m)
#pragma unroll
      for (int w = 0; w < 2; ++w)
#pragma unroll
        for (int n = 0; n < 2; ++n)
          acc[m][w][n] = __builtin_amdgcn_mfma_f32_16x16x32_bf16(a1[m], b1[w][n], acc[m][w][n], 0, 0, 0);
    __builtin_amdgcn_s_setprio(0);
    if (ktl + 1 < KTS) {
      // complete A(ktl+1) (+ B(ktl+2), older) before the shared barrier
      if (ktl + 3 < KTS)      waitv<12>();   // leaves [B(ktl+3)x8, A(ktl+2)x4]
      else if (ktl + 2 < KTS) waitv<4>();    // leaves [A(ktl+2)x4]
      else                    waitv<0>();
      asm volatile("s_waitcnt lgkmcnt(0)" ::: "memory");  // BWRITE + reads drained
      __builtin_amdgcn_sched_barrier(0);
      __builtin_amdgcn_s_barrier();
      __builtin_amdgcn_sched_barrier(0);
    }
  };

#pragma unroll 1
  for (int kt2 = 0; kt2 < KTS; kt2 += 2) {
    ITER(kt2, rbB);       // writes B(kt2+1) from rbB, loads B(kt2+3) into rbB
    ITER(kt2 + 1, rbA);   // writes B(kt2+2) from rbA, loads B(kt2+4) into rbA
  }

  // ---- epilogue ----
  if constexpr (MODE == 1) {
    unsigned short* H = (unsigned short*)OUT + (size_t)e * CAP * NOUT;
#pragma unroll
    for (int m = 0; m < 8; ++m) {
#pragma unroll
      for (int n = 0; n < 2; ++n) {
        int row0 = bm * 256 + wr * 128 + m * 16 + lhi * 4;
        int col = bn * 128 + wc * 32 + n * 16 + lane15;
#pragma unroll
        for (int j = 0; j < 4; ++j) {
          float g1 = acc[m][0][n][j];
          float g3 = acc[m][1][n][j];
          float hv = g1 / (1.0f + __expf(-g1)) * g3;
          H[(size_t)(row0 + j) * NOUT + col] = f2bf(hv);
        }
      }
    }
  } else {
    // ungated split-K partial: one writer per (sk, e, row, col)
    float* P = (float*)OUT + (size_t)sk * 8 * CAP * NOUT + (size_t)e * CAP * NOUT;
#pragma unroll
    for (int m = 0; m < 8; ++m) {
#pragma unroll
      for (int w = 0; w < 2; ++w) {
#pragma unroll
        for (int n = 0; n < 2; ++n) {
          int row0 = bm * 256 + wr * 128 + m * 16 + lhi * 4;
          int col = bn * BNCOL + w * 128 + wc * 32 + n * 16 + lane15;
#pragma unroll
          for (int j = 0; j < 4; ++j)
            P[(size_t)(row0 + j) * NOUT + col] = acc[m][w][n][j];
        }
      }
    }
  }
}

// ---------------- combine: out[t] = sum_k g_k * (P0[e_k,s_k] + P1[e_k,s_k]) ----------------
__global__ void combine_kernel(const float* __restrict__ ob, const int* __restrict__ topi,
                               const float* __restrict__ gall, const int* __restrict__ slot,
                               float* __restrict__ out) {
  int t = blockIdx.x;
  int d = threadIdx.x * 4;
  const size_t HALF = (size_t)8 * CAP * D_MODEL;
  float4 r = make_float4(0.f, 0.f, 0.f, 0.f);
#pragma unroll
  for (int k = 0; k < 2; ++k) {
    int s = slot[t * 2 + k];
    if (s >= 0) {
      int e = topi[t * 2 + k];
      float g = gall[t * 2 + k];
      size_t base = ((size_t)e * CAP + s) * D_MODEL + d;
      float4 a = *(const float4*)(ob + base);
      float4 b = *(const float4*)(ob + HALF + base);
      r.x += g * (a.x + b.x); r.y += g * (a.y + b.y);
      r.z += g * (a.z + b.z); r.w += g * (a.w + b.w);
    }
  }
  *(float4*)(out + (size_t)t * D_MODEL + d) = r;
}

extern "C" void kernel_launch(void* const* d_in, const int* in_sizes, int n_in,
                              void* d_out, int out_size, void* d_ws, size_t ws_size,
                              hipStream_t stream) {
  const float* x     = (const float*)d_in[0];
  const float* noise = (const float*)d_in[1];
  const float* rw    = (const float*)d_in[2];
  const float* rb    = (const float*)d_in[3];
  const float* nw    = (const float*)d_in[4];
  const float* nb    = (const float*)d_in[5];
  const float* w1    = (const float*)d_in[6];
  const float* w3    = (const float*)d_in[7];
  const float* w2    = (const float*)d_in[8];
  float* out = (float*)d_out;

  char* ws = (char*)d_ws;
  size_t off = 0;
  auto alloc = [&](size_t bytes) -> void* {
    void* p = ws + off;
    off += (bytes + 255) & ~(size_t)255;
    return p;
  };
  unsigned short* xb = (unsigned short*)alloc((size_t)8 * CAP * D_MODEL * 2);
  unsigned short* h  = (unsigned short*)alloc((size_t)8 * CAP * HIDDEN * 2);
  float*          ob = (float*)alloc((size_t)2 * 8 * CAP * D_MODEL * 4);  // 2 split-K partials
  int*   topi  = (int*)alloc(N_TOK * 2 * 4);
  float* gall  = (float*)alloc(N_TOK * 2 * 4);
  int*   slot  = (int*)alloc(N_TOK * 2 * 4);
  int*   tokl  = (int*)alloc(8 * CAP * 4);
  (void)ws_size; (void)in_sizes; (void)n_in; (void)out_size;

  router_kernel<<<N_TOK / 4, 256, 0, stream>>>(x, noise, rw, rb, nw, nb, topi, gall, slot);
  scan_kernel<<<8, 1024, 0, stream>>>(topi, slot, tokl);
  gather_kernel<<<8 * CAP, 256, 0, stream>>>(x, tokl, xb);

  // FUSE GEMM12 + silu, f32 weights in-kernel: h = silu(xb@w1^T)*(xb@w3^T). 704 wgs.
  gemm_moe<HIDDEN, D_MODEL, 1><<<dim3(704), 512, 0, stream>>>(xb, w1, w3, (void*)h);

  // PART GEMM3: ob[sk] = h @ w2^T partials, f32 weights in-kernel. 256 wgs.
  gemm_moe<D_MODEL, HIDDEN, 2><<<dim3(256), 512, 0, stream>>>(
      h, w2, w2 + (size_t)128 * HIDDEN, (void*)ob);

  // combine partials with gates; plain stores (no memset needed)
  combine_kernel<<<N_TOK, 256, 0, stream>>>(ob, topi, gall, slot, out);
}

// Round 9
// 369.721 us; speedup vs baseline: 2.1731x; 2.1731x over previous
//
#include <hip/hip_runtime.h>

// SparseMoE: B=2,S=2048 -> N=4096 tokens, D=1024, HIDDEN=2816, 8 experts, top-2, cap=1024
// Round 9: consolidation. Revert to round-6 GEMM cores (precvt bf16 weights + pure
// global_load_lds staging — reg-staged B is structurally worse: rounds 3/7/8, guide m151).
// New lever: cvt3 merged INTO the router launch (prep_kernel) so the BW-bound weight
// conversion runs concurrently with the compute-ish router -> hides ~15-25us + 1 launch.
// Register budget note: acc[8][2][2]=128 AGPRs of the 256/wave unified file (2 waves/SIMD)
// caps arch VGPRs at 128 — any B reg-staging buffer spills (round-8 lesson).

#define D_MODEL 1024
#define HIDDEN 2816
#define N_TOK 4096
#define CAP 1024

typedef __attribute__((ext_vector_type(8))) short short8;
typedef __attribute__((ext_vector_type(4))) float f32x4;

__device__ __forceinline__ unsigned short f2bf(float f) {
  unsigned int u = __float_as_uint(f);
  u += 0x7fffu + ((u >> 16) & 1u);   // RNE
  return (unsigned short)(u >> 16);
}
__device__ __forceinline__ float bf2f(unsigned short h) {
  return __uint_as_float(((unsigned int)h) << 16);
}

template <int Ncnt> __device__ __forceinline__ void waitv() {
  if constexpr (Ncnt == 8)      asm volatile("s_waitcnt vmcnt(8)" ::: "memory");
  else if constexpr (Ncnt == 6) asm volatile("s_waitcnt vmcnt(6)" ::: "memory");
  else                          asm volatile("s_waitcnt vmcnt(0)" ::: "memory");
}

// ---------------- prep: router (blocks 0..1023) + weight cvt (blocks 1024+) ----------------
// Router: noisy top-2 gates per token, 4 tokens/block (1 wave each), f64 dots.
// Cvt: w1|w3|w2 f32 -> contiguous bf16 wb (3*WELEM elems), 1 float4/thread.
__global__ void prep_kernel(const float* __restrict__ x, const float* __restrict__ noise,
                            const float* __restrict__ rw, const float* __restrict__ rb,
                            const float* __restrict__ nw, const float* __restrict__ nb,
                            const float* __restrict__ w1, const float* __restrict__ w3,
                            const float* __restrict__ w2, unsigned short* __restrict__ wb,
                            int* __restrict__ topi, float* __restrict__ gall,
                            int* __restrict__ slot) {
  if (blockIdx.x >= 1024) {
    constexpr size_t Q = (size_t)8 * HIDDEN * D_MODEL / 4;   // float4s per weight array
    size_t i = (size_t)(blockIdx.x - 1024) * 256 + threadIdx.x;
    const float* src;
    size_t off;
    if (i < Q)          { src = w1; off = i; }
    else if (i < 2 * Q) { src = w3; off = i - Q; }
    else                { src = w2; off = i - 2 * Q; }
    float4 v = *(const float4*)(src + off * 4);
    *(ushort4*)(wb + i * 4) = make_ushort4(f2bf(v.x), f2bf(v.y), f2bf(v.z), f2bf(v.w));
    return;
  }
  int wid = threadIdx.x >> 6;
  int lane = threadIdx.x & 63;
  int t = blockIdx.x * 4 + wid;
  const float* xr = x + (size_t)t * D_MODEL;
  double accL[8] = {0,0,0,0,0,0,0,0};
  double accN[8] = {0,0,0,0,0,0,0,0};
  for (int i = 0; i < 4; ++i) {
    int kb = (i * 64 + lane) * 4;
    float4 xv = *(const float4*)(xr + kb);
#pragma unroll
    for (int e = 0; e < 8; ++e) {
      float4 wv = *(const float4*)(rw + e * D_MODEL + kb);
      accL[e] += (double)xv.x * wv.x + (double)xv.y * wv.y + (double)xv.z * wv.z + (double)xv.w * wv.w;
      float4 nv = *(const float4*)(nw + e * D_MODEL + kb);
      accN[e] += (double)xv.x * nv.x + (double)xv.y * nv.y + (double)xv.z * nv.z + (double)xv.w * nv.w;
    }
  }
#pragma unroll
  for (int e = 0; e < 8; ++e) {
    for (int s = 32; s > 0; s >>= 1) {
      accL[e] += __shfl_xor(accL[e], s);
      accN[e] += __shfl_xor(accN[e], s);
    }
  }
  if (lane == 0) {
    double noisy[8];
#pragma unroll
    for (int e = 0; e < 8; ++e) {
      double lg = accL[e] + (double)rb[e];
      double nl = accN[e] + (double)nb[e];
      double sp = (nl > 0.0 ? nl : 0.0) + log1p(exp(-fabs(nl)));  // softplus, stable
      noisy[e] = lg + (double)noise[t * 8 + e] * sp;
    }
    int i0 = 0;
    for (int e = 1; e < 8; ++e) if (noisy[e] > noisy[i0]) i0 = e;
    int i1 = -1;
    for (int e = 0; e < 8; ++e) { if (e == i0) continue; if (i1 < 0 || noisy[e] > noisy[i1]) i1 = e; }
    double g0 = 1.0 / (1.0 + exp(noisy[i1] - noisy[i0]));
    topi[t * 2] = i0; topi[t * 2 + 1] = i1;
    gall[t * 2] = (float)g0; gall[t * 2 + 1] = (float)(1.0 - g0);
    slot[t * 2] = -1; slot[t * 2 + 1] = -1;
  }
}

// ---------------- per-expert capacity scan (token-index order) ----------------
__global__ void scan_kernel(const int* __restrict__ topi,
                            int* __restrict__ slot, int* __restrict__ tok_list) {
  int e = blockIdx.x;
  int tid = threadIdx.x;
  int lane = tid & 63, wid = tid >> 6;
  __shared__ int wsum[16];
  __shared__ int base_s;
  tok_list[e * CAP + tid] = -1;
  if (tid == 0) base_s = 0;
  __syncthreads();
  for (int chunk = 0; chunk < N_TOK / 1024; ++chunk) {
    int t = chunk * 1024 + tid;
    int i0 = topi[t * 2], i1 = topi[t * 2 + 1];
    bool m = (i0 == e) || (i1 == e);
    unsigned long long mask = __ballot(m);
    int excl = __popcll(mask & ((1ull << lane) - 1ull));
    if (lane == 0) wsum[wid] = __popcll(mask);
    __syncthreads();
    int base = base_s;
    int woff = 0;
    for (int w = 0; w < wid; ++w) woff += wsum[w];
    int pos = base + woff + excl;
    if (m && pos < CAP) {
      tok_list[e * CAP + pos] = t;
      if (i0 == e) slot[t * 2] = pos; else slot[t * 2 + 1] = pos;
    }
    __syncthreads();
    if (tid == 0) {
      int s = 0;
      for (int w = 0; w < 16; ++w) s += wsum[w];
      base_s = base + s;
    }
    __syncthreads();
  }
}

// ---------------- gather x rows into per-expert bf16 buffers ----------------
__global__ void gather_kernel(const float* __restrict__ x, const int* __restrict__ tok_list,
                              unsigned short* __restrict__ xb) {
  int row = blockIdx.x;
  int tok = tok_list[row];
  unsigned short* dst = xb + (size_t)row * D_MODEL + threadIdx.x * 4;
  if (tok < 0) {
    *(ushort4*)dst = make_ushort4(0, 0, 0, 0);
  } else {
    float4 v = *(const float4*)(x + (size_t)tok * D_MODEL + threadIdx.x * 4);
    *(ushort4*)dst = make_ushort4(f2bf(v.x), f2bf(v.y), f2bf(v.z), f2bf(v.w));
  }
}

// ============ grouped GEMM core (gload_lds + src-swizzle + counted vmcnt) ============
// BM=256, 8 waves (2M x 4N), NW B-panels of 128 cols each, optional split-K.
// MODE 1 (FUSE): panels = w1,w3 at same cols; epilogue silu(acc0)*acc1 -> bf16 h.
// MODE 2 (PART): panels = adjacent 128-col halves of w2 (BNCOL=256), split-K SK=2;
//                epilogue stores ungated f32 partials (no atomics).
template <int NOUT, int K, int NW, int MODE>
__global__ __launch_bounds__(512, 1)
void gemm_moe(const unsigned short* __restrict__ Ab, const unsigned short* __restrict__ B0,
              const unsigned short* __restrict__ B1, void* __restrict__ OUT) {
  constexpr int ABYTES = 32768;
  constexpr int BUFSZ = ABYTES + NW * 16384;
  constexpr int KT = K / 64;
  constexpr int SK = (MODE == 2) ? 2 : 1;
  constexpr int KTS = KT / SK;
  constexpr int BNCOL = (MODE == 2 && NW == 2) ? 256 : 128;
  constexpr int NBN = NOUT / BNCOL;
  constexpr int NWG = 8 * 4 * NBN * SK;
  constexpr int CPW = (32 + NW * 16) / 8;   // gload_lds per thread per stage: 8 or 6

  __shared__ char smem[2 * BUFSZ];

  // bijective XCD swizzle + decode (NWG % 8 == 0)
  int lid = blockIdx.x;
  int swz = (lid & 7) * (NWG / 8) + (lid >> 3);
  constexpr int PERE = 4 * NBN * SK;
  int e = swz / PERE;
  int r = swz - e * PERE;
  int bm = r / (NBN * SK);
  int r2 = r - bm * (NBN * SK);
  int bn = r2 / SK;
  int sk = r2 - bn * SK;
  int kt0 = sk * KTS;

  const unsigned short* A = Ab + (size_t)e * CAP * K;
  int tid = threadIdx.x, lane = tid & 63, wid = tid >> 6;
  int wr = wid >> 2, wc = wid & 3;
  int lane15 = lane & 15, lhi = lane >> 4, l7 = lane & 7;

  // stage source: pre-swizzled global address (16B slot ^= row&7), linear LDS dest
  int lrow = lane >> 3;
  int lcol = ((lane & 7) ^ lrow) * 8;
  const unsigned short* Abase = A + (size_t)(bm * 256 + lrow) * K + lcol;
  const unsigned short* Bb0 = B0 + (size_t)e * NOUT * K + (size_t)(bn * BNCOL + lrow) * K + lcol;
  const unsigned short* Bb1 = (NW == 2)
      ? B1 + (size_t)e * NOUT * K + (size_t)(bn * BNCOL + lrow) * K + lcol : Bb0;

  auto STAGE = [&](int ktile, int buf) {
    char* lb = smem + buf * BUFSZ;
#pragma unroll
    for (int i = 0; i < CPW; ++i) {
      int c = wid * CPW + i;
      if (c < 32) {
        const unsigned short* g = Abase + (size_t)(c * 8) * K + ktile * 64;
        __builtin_amdgcn_global_load_lds((const __attribute__((address_space(1))) void*)g,
                                         (__attribute__((address_space(3))) void*)(lb + c * 1024), 16, 0, 0);
      } else {
        int cb2 = c - 32;
        const unsigned short* base = (cb2 >> 4) ? Bb1 : Bb0;
        const unsigned short* g = base + (size_t)((cb2 & 15) * 8) * K + ktile * 64;
        __builtin_amdgcn_global_load_lds((const __attribute__((address_space(1))) void*)g,
                                         (__attribute__((address_space(3))) void*)(lb + ABYTES + cb2 * 1024), 16, 0, 0);
      }
    }
  };

  // swizzled ds_read slot offsets (same involution)
  int sw0 = ((0 + lhi) ^ l7) * 16;
  int sw1 = ((4 + lhi) ^ l7) * 16;

  f32x4 acc[8][NW][2] = {};

  // ---- prologue: stage tiles kt0, kt0+1 ----
  STAGE(kt0, 0);
  STAGE(kt0 + 1, 1);
  waitv<CPW>();
  __builtin_amdgcn_sched_barrier(0);
  __builtin_amdgcn_s_barrier();
  __builtin_amdgcn_sched_barrier(0);

  for (int ktl = 0; ktl < KTS; ++ktl) {
    char* cb = smem + (ktl & 1) * BUFSZ;
    short8 a0[8], b0[NW][2], a1[8], b1[NW][2];
#pragma unroll
    for (int w = 0; w < NW; ++w)
#pragma unroll
      for (int n = 0; n < 2; ++n)
        b0[w][n] = *(const short8*)(cb + ABYTES + w * 16384 + wc * 4096 + n * 2048 + lane15 * 128 + sw0);
#pragma unroll
    for (int m = 0; m < 8; ++m)
      a0[m] = *(const short8*)(cb + wr * 16384 + m * 2048 + lane15 * 128 + sw0);
    __builtin_amdgcn_s_setprio(1);
#pragma unroll
    for (int m = 0; m < 8; ++m)
#pragma unroll
      for (int w = 0; w < NW; ++w)
#pragma unroll
        for (int n = 0; n < 2; ++n)
          acc[m][w][n] = __builtin_amdgcn_mfma_f32_16x16x32_bf16(a0[m], b0[w][n], acc[m][w][n], 0, 0, 0);
    __builtin_amdgcn_s_setprio(0);
#pragma unroll
    for (int w = 0; w < NW; ++w)
#pragma unroll
      for (int n = 0; n < 2; ++n)
        b1[w][n] = *(const short8*)(cb + ABYTES + w * 16384 + wc * 4096 + n * 2048 + lane15 * 128 + sw1);
#pragma unroll
    for (int m = 0; m < 8; ++m)
      a1[m] = *(const short8*)(cb + wr * 16384 + m * 2048 + lane15 * 128 + sw1);
    // all ds_reads of this buffer issued -> safe to overwrite after barrier
    __builtin_amdgcn_sched_barrier(0);
    __builtin_amdgcn_s_barrier();
    __builtin_amdgcn_sched_barrier(0);
    if (ktl + 2 < KTS) STAGE(kt0 + ktl + 2, ktl & 1);
    __builtin_amdgcn_s_setprio(1);
#pragma unroll
    for (int m = 0; m < 8; ++m)
#pragma unroll
      for (int w = 0; w < NW; ++w)
#pragma unroll
        for (int n = 0; n < 2; ++n)
          acc[m][w][n] = __builtin_amdgcn_mfma_f32_16x16x32_bf16(a1[m], b1[w][n], acc[m][w][n], 0, 0, 0);
    __builtin_amdgcn_s_setprio(0);
    if (ktl + 2 < KTS) waitv<CPW>();
    else if (ktl + 1 < KTS) waitv<0>();
    __builtin_amdgcn_sched_barrier(0);
    if (ktl + 1 < KTS) __builtin_amdgcn_s_barrier();
    __builtin_amdgcn_sched_barrier(0);
  }

  // ---- epilogue ----
  if constexpr (MODE == 1) {
    unsigned short* H = (unsigned short*)OUT + (size_t)e * CAP * NOUT;
#pragma unroll
    for (int m = 0; m < 8; ++m) {
#pragma unroll
      for (int n = 0; n < 2; ++n) {
        int row0 = bm * 256 + wr * 128 + m * 16 + lhi * 4;
        int col = bn * 128 + wc * 32 + n * 16 + lane15;
#pragma unroll
        for (int j = 0; j < 4; ++j) {
          float g1 = acc[m][0][n][j];
          float g3 = acc[m][1][n][j];
          float hv = g1 / (1.0f + __expf(-g1)) * g3;
          H[(size_t)(row0 + j) * NOUT + col] = f2bf(hv);
        }
      }
    }
  } else {
    // ungated split-K partial: one writer per (sk, e, row, col)
    float* P = (float*)OUT + (size_t)sk * 8 * CAP * NOUT + (size_t)e * CAP * NOUT;
#pragma unroll
    for (int m = 0; m < 8; ++m) {
#pragma unroll
      for (int w = 0; w < NW; ++w) {
#pragma unroll
        for (int n = 0; n < 2; ++n) {
          int row0 = bm * 256 + wr * 128 + m * 16 + lhi * 4;
          int col = bn * BNCOL + w * 128 + wc * 32 + n * 16 + lane15;
#pragma unroll
          for (int j = 0; j < 4; ++j)
            P[(size_t)(row0 + j) * NOUT + col] = acc[m][w][n][j];
        }
      }
    }
  }
}

// ---------------- combine: out[t] = sum_k g_k * (P0[e_k,s_k] + P1[e_k,s_k]) ----------------
__global__ void combine_kernel(const float* __restrict__ ob, const int* __restrict__ topi,
                               const float* __restrict__ gall, const int* __restrict__ slot,
                               float* __restrict__ out) {
  int t = blockIdx.x;
  int d = threadIdx.x * 4;
  const size_t HALF = (size_t)8 * CAP * D_MODEL;
  float4 r = make_float4(0.f, 0.f, 0.f, 0.f);
#pragma unroll
  for (int k = 0; k < 2; ++k) {
    int s = slot[t * 2 + k];
    if (s >= 0) {
      int e = topi[t * 2 + k];
      float g = gall[t * 2 + k];
      size_t base = ((size_t)e * CAP + s) * D_MODEL + d;
      float4 a = *(const float4*)(ob + base);
      float4 b = *(const float4*)(ob + HALF + base);
      r.x += g * (a.x + b.x); r.y += g * (a.y + b.y);
      r.z += g * (a.z + b.z); r.w += g * (a.w + b.w);
    }
  }
  *(float4*)(out + (size_t)t * D_MODEL + d) = r;
}

extern "C" void kernel_launch(void* const* d_in, const int* in_sizes, int n_in,
                              void* d_out, int out_size, void* d_ws, size_t ws_size,
                              hipStream_t stream) {
  const float* x     = (const float*)d_in[0];
  const float* noise = (const float*)d_in[1];
  const float* rw    = (const float*)d_in[2];
  const float* rb    = (const float*)d_in[3];
  const float* nw    = (const float*)d_in[4];
  const float* nb    = (const float*)d_in[5];
  const float* w1    = (const float*)d_in[6];
  const float* w3    = (const float*)d_in[7];
  const float* w2    = (const float*)d_in[8];
  float* out = (float*)d_out;

  char* ws = (char*)d_ws;
  size_t off = 0;
  auto alloc = [&](size_t bytes) -> void* {
    void* p = ws + off;
    off += (bytes + 255) & ~(size_t)255;
    return p;
  };
  const size_t WELEM = (size_t)8 * HIDDEN * D_MODEL;          // 23,068,672
  unsigned short* wb = (unsigned short*)alloc(3 * WELEM * 2); // wb1|wb3|wb2 contiguous
  unsigned short* xb = (unsigned short*)alloc((size_t)8 * CAP * D_MODEL * 2);
  unsigned short* h  = (unsigned short*)alloc((size_t)8 * CAP * HIDDEN * 2);
  float*          ob = (float*)alloc((size_t)2 * 8 * CAP * D_MODEL * 4);  // 2 split-K partials
  int*   topi  = (int*)alloc(N_TOK * 2 * 4);
  float* gall  = (float*)alloc(N_TOK * 2 * 4);
  int*   slot  = (int*)alloc(N_TOK * 2 * 4);
  int*   tokl  = (int*)alloc(8 * CAP * 4);
  (void)ws_size; (void)in_sizes; (void)n_in; (void)out_size;

  unsigned short* wb1 = wb;
  unsigned short* wb3 = wb + WELEM;
  unsigned short* wb2 = wb + 2 * WELEM;

  // prep: router (1024 blocks) + weight cvt (67584 blocks) in one concurrent dispatch
  const int cvt_blocks = (int)(3 * WELEM / 4 / 256);   // 67584
  prep_kernel<<<1024 + cvt_blocks, 256, 0, stream>>>(
      x, noise, rw, rb, nw, nb, w1, w3, w2, wb, topi, gall, slot);

  scan_kernel<<<8, 1024, 0, stream>>>(topi, slot, tokl);
  gather_kernel<<<8 * CAP, 256, 0, stream>>>(x, tokl, xb);

  // FUSE GEMM12 + silu: h = silu(xb@w1^T) * (xb@w3^T), bf16. 8e*4bm*22bn = 704 wgs.
  gemm_moe<HIDDEN, D_MODEL, 2, 1><<<dim3(704), 512, 0, stream>>>(xb, wb1, wb3, (void*)h);

  // PART GEMM3: ob[sk] = h @ w2^T partials. BN=256, split-K2: 256 wgs.
  gemm_moe<D_MODEL, HIDDEN, 2, 2><<<dim3(256), 512, 0, stream>>>(
      h, wb2, wb2 + (size_t)128 * HIDDEN, (void*)ob);

  // combine partials with gates; plain stores (no memset needed)
  combine_kernel<<<N_TOK, 256, 0, stream>>>(ob, topi, gall, slot, out);
}

// Round 10
// 320.326 us; speedup vs baseline: 2.5082x; 1.1542x over previous
//
#include <hip/hip_runtime.h>

// SparseMoE: B=2,S=2048 -> N=4096 tokens, D=1024, HIDDEN=2816, 8 experts, top-2, cap=1024
// Round 10: r9 structure with prep fixed. r9's prep regression = joint register
// allocation (VGPR=44 = exactly the f64 accumulators) starving the router branch.
// Fix: __launch_bounds__(256,2) (<=128 VGPR) + cvt blocks first / router at tail.
// GEMM cores = round-6 proven (precvt bf16 + gload_lds; in-GEMM f32 B is HBM-cadence-
// bound: 64KB f32/step/CU > 24.6 KB/us fair share — r7/r8 lesson).

#define D_MODEL 1024
#define HIDDEN 2816
#define N_TOK 4096
#define CAP 1024

typedef __attribute__((ext_vector_type(8))) short short8;
typedef __attribute__((ext_vector_type(4))) float f32x4;

__device__ __forceinline__ unsigned short f2bf(float f) {
  unsigned int u = __float_as_uint(f);
  u += 0x7fffu + ((u >> 16) & 1u);   // RNE
  return (unsigned short)(u >> 16);
}
__device__ __forceinline__ float bf2f(unsigned short h) {
  return __uint_as_float(((unsigned int)h) << 16);
}

template <int Ncnt> __device__ __forceinline__ void waitv() {
  if constexpr (Ncnt == 8)      asm volatile("s_waitcnt vmcnt(8)" ::: "memory");
  else if constexpr (Ncnt == 6) asm volatile("s_waitcnt vmcnt(6)" ::: "memory");
  else                          asm volatile("s_waitcnt vmcnt(0)" ::: "memory");
}

#define CVT_BLOCKS 67584   // 3*WELEM/4/256

// ---------------- prep: weight cvt (blocks 0..CVT_BLOCKS-1) + router (tail 1024) ----------------
__global__ __launch_bounds__(256, 2)
void prep_kernel(const float* __restrict__ x, const float* __restrict__ noise,
                 const float* __restrict__ rw, const float* __restrict__ rb,
                 const float* __restrict__ nw, const float* __restrict__ nb,
                 const float* __restrict__ w1, const float* __restrict__ w3,
                 const float* __restrict__ w2, unsigned short* __restrict__ wb,
                 int* __restrict__ topi, float* __restrict__ gall,
                 int* __restrict__ slot) {
  if (blockIdx.x < CVT_BLOCKS) {
    constexpr size_t Q = (size_t)8 * HIDDEN * D_MODEL / 4;   // float4s per weight array
    size_t i = (size_t)blockIdx.x * 256 + threadIdx.x;
    const float* src;
    size_t off;
    if (i < Q)          { src = w1; off = i; }
    else if (i < 2 * Q) { src = w3; off = i - Q; }
    else                { src = w2; off = i - 2 * Q; }
    float4 v = *(const float4*)(src + off * 4);
    *(ushort4*)(wb + i * 4) = make_ushort4(f2bf(v.x), f2bf(v.y), f2bf(v.z), f2bf(v.w));
    return;
  }
  int wid = threadIdx.x >> 6;
  int lane = threadIdx.x & 63;
  int t = (blockIdx.x - CVT_BLOCKS) * 4 + wid;
  const float* xr = x + (size_t)t * D_MODEL;
  double accL[8] = {0,0,0,0,0,0,0,0};
  double accN[8] = {0,0,0,0,0,0,0,0};
  for (int i = 0; i < 4; ++i) {
    int kb = (i * 64 + lane) * 4;
    float4 xv = *(const float4*)(xr + kb);
#pragma unroll
    for (int e = 0; e < 8; ++e) {
      float4 wv = *(const float4*)(rw + e * D_MODEL + kb);
      accL[e] += (double)xv.x * wv.x + (double)xv.y * wv.y + (double)xv.z * wv.z + (double)xv.w * wv.w;
      float4 nv = *(const float4*)(nw + e * D_MODEL + kb);
      accN[e] += (double)xv.x * nv.x + (double)xv.y * nv.y + (double)xv.z * nv.z + (double)xv.w * nv.w;
    }
  }
#pragma unroll
  for (int e = 0; e < 8; ++e) {
    for (int s = 32; s > 0; s >>= 1) {
      accL[e] += __shfl_xor(accL[e], s);
      accN[e] += __shfl_xor(accN[e], s);
    }
  }
  if (lane == 0) {
    double noisy[8];
#pragma unroll
    for (int e = 0; e < 8; ++e) {
      double lg = accL[e] + (double)rb[e];
      double nl = accN[e] + (double)nb[e];
      double sp = (nl > 0.0 ? nl : 0.0) + log1p(exp(-fabs(nl)));  // softplus, stable
      noisy[e] = lg + (double)noise[t * 8 + e] * sp;
    }
    int i0 = 0;
    for (int e = 1; e < 8; ++e) if (noisy[e] > noisy[i0]) i0 = e;
    int i1 = -1;
    for (int e = 0; e < 8; ++e) { if (e == i0) continue; if (i1 < 0 || noisy[e] > noisy[i1]) i1 = e; }
    double g0 = 1.0 / (1.0 + exp(noisy[i1] - noisy[i0]));
    topi[t * 2] = i0; topi[t * 2 + 1] = i1;
    gall[t * 2] = (float)g0; gall[t * 2 + 1] = (float)(1.0 - g0);
    slot[t * 2] = -1; slot[t * 2 + 1] = -1;
  }
}

// ---------------- per-expert capacity scan (token-index order) ----------------
__global__ void scan_kernel(const int* __restrict__ topi,
                            int* __restrict__ slot, int* __restrict__ tok_list) {
  int e = blockIdx.x;
  int tid = threadIdx.x;
  int lane = tid & 63, wid = tid >> 6;
  __shared__ int wsum[16];
  __shared__ int base_s;
  tok_list[e * CAP + tid] = -1;
  if (tid == 0) base_s = 0;
  __syncthreads();
  for (int chunk = 0; chunk < N_TOK / 1024; ++chunk) {
    int t = chunk * 1024 + tid;
    int i0 = topi[t * 2], i1 = topi[t * 2 + 1];
    bool m = (i0 == e) || (i1 == e);
    unsigned long long mask = __ballot(m);
    int excl = __popcll(mask & ((1ull << lane) - 1ull));
    if (lane == 0) wsum[wid] = __popcll(mask);
    __syncthreads();
    int base = base_s;
    int woff = 0;
    for (int w = 0; w < wid; ++w) woff += wsum[w];
    int pos = base + woff + excl;
    if (m && pos < CAP) {
      tok_list[e * CAP + pos] = t;
      if (i0 == e) slot[t * 2] = pos; else slot[t * 2 + 1] = pos;
    }
    __syncthreads();
    if (tid == 0) {
      int s = 0;
      for (int w = 0; w < 16; ++w) s += wsum[w];
      base_s = base + s;
    }
    __syncthreads();
  }
}

// ---------------- gather x rows into per-expert bf16 buffers ----------------
__global__ void gather_kernel(const float* __restrict__ x, const int* __restrict__ tok_list,
                              unsigned short* __restrict__ xb) {
  int row = blockIdx.x;
  int tok = tok_list[row];
  unsigned short* dst = xb + (size_t)row * D_MODEL + threadIdx.x * 4;
  if (tok < 0) {
    *(ushort4*)dst = make_ushort4(0, 0, 0, 0);
  } else {
    float4 v = *(const float4*)(x + (size_t)tok * D_MODEL + threadIdx.x * 4);
    *(ushort4*)dst = make_ushort4(f2bf(v.x), f2bf(v.y), f2bf(v.z), f2bf(v.w));
  }
}

// ============ grouped GEMM core (gload_lds + src-swizzle + counted vmcnt) ============
// BM=256, 8 waves (2M x 4N), NW B-panels of 128 cols each, optional split-K.
// MODE 1 (FUSE): panels = w1,w3 at same cols; epilogue silu(acc0)*acc1 -> bf16 h.
// MODE 2 (PART): panels = adjacent 128-col halves of w2 (BNCOL=256), split-K SK=2;
//                epilogue stores ungated f32 partials (no atomics).
template <int NOUT, int K, int NW, int MODE>
__global__ __launch_bounds__(512, 1)
void gemm_moe(const unsigned short* __restrict__ Ab, const unsigned short* __restrict__ B0,
              const unsigned short* __restrict__ B1, void* __restrict__ OUT) {
  constexpr int ABYTES = 32768;
  constexpr int BUFSZ = ABYTES + NW * 16384;
  constexpr int KT = K / 64;
  constexpr int SK = (MODE == 2) ? 2 : 1;
  constexpr int KTS = KT / SK;
  constexpr int BNCOL = (MODE == 2 && NW == 2) ? 256 : 128;
  constexpr int NBN = NOUT / BNCOL;
  constexpr int NWG = 8 * 4 * NBN * SK;
  constexpr int CPW = (32 + NW * 16) / 8;   // gload_lds per thread per stage: 8 or 6

  __shared__ char smem[2 * BUFSZ];

  // bijective XCD swizzle + decode (NWG % 8 == 0)
  int lid = blockIdx.x;
  int swz = (lid & 7) * (NWG / 8) + (lid >> 3);
  constexpr int PERE = 4 * NBN * SK;
  int e = swz / PERE;
  int r = swz - e * PERE;
  int bm = r / (NBN * SK);
  int r2 = r - bm * (NBN * SK);
  int bn = r2 / SK;
  int sk = r2 - bn * SK;
  int kt0 = sk * KTS;

  const unsigned short* A = Ab + (size_t)e * CAP * K;
  int tid = threadIdx.x, lane = tid & 63, wid = tid >> 6;
  int wr = wid >> 2, wc = wid & 3;
  int lane15 = lane & 15, lhi = lane >> 4, l7 = lane & 7;

  // stage source: pre-swizzled global address (16B slot ^= row&7), linear LDS dest
  int lrow = lane >> 3;
  int lcol = ((lane & 7) ^ lrow) * 8;
  const unsigned short* Abase = A + (size_t)(bm * 256 + lrow) * K + lcol;
  const unsigned short* Bb0 = B0 + (size_t)e * NOUT * K + (size_t)(bn * BNCOL + lrow) * K + lcol;
  const unsigned short* Bb1 = (NW == 2)
      ? B1 + (size_t)e * NOUT * K + (size_t)(bn * BNCOL + lrow) * K + lcol : Bb0;

  auto STAGE = [&](int ktile, int buf) {
    char* lb = smem + buf * BUFSZ;
#pragma unroll
    for (int i = 0; i < CPW; ++i) {
      int c = wid * CPW + i;
      if (c < 32) {
        const unsigned short* g = Abase + (size_t)(c * 8) * K + ktile * 64;
        __builtin_amdgcn_global_load_lds((const __attribute__((address_space(1))) void*)g,
                                         (__attribute__((address_space(3))) void*)(lb + c * 1024), 16, 0, 0);
      } else {
        int cb2 = c - 32;
        const unsigned short* base = (cb2 >> 4) ? Bb1 : Bb0;
        const unsigned short* g = base + (size_t)((cb2 & 15) * 8) * K + ktile * 64;
        __builtin_amdgcn_global_load_lds((const __attribute__((address_space(1))) void*)g,
                                         (__attribute__((address_space(3))) void*)(lb + ABYTES + cb2 * 1024), 16, 0, 0);
      }
    }
  };

  // swizzled ds_read slot offsets (same involution)
  int sw0 = ((0 + lhi) ^ l7) * 16;
  int sw1 = ((4 + lhi) ^ l7) * 16;

  f32x4 acc[8][NW][2] = {};

  // ---- prologue: stage tiles kt0, kt0+1 ----
  STAGE(kt0, 0);
  STAGE(kt0 + 1, 1);
  waitv<CPW>();
  __builtin_amdgcn_sched_barrier(0);
  __builtin_amdgcn_s_barrier();
  __builtin_amdgcn_sched_barrier(0);

  for (int ktl = 0; ktl < KTS; ++ktl) {
    char* cb = smem + (ktl & 1) * BUFSZ;
    short8 a0[8], b0[NW][2], a1[8], b1[NW][2];
#pragma unroll
    for (int w = 0; w < NW; ++w)
#pragma unroll
      for (int n = 0; n < 2; ++n)
        b0[w][n] = *(const short8*)(cb + ABYTES + w * 16384 + wc * 4096 + n * 2048 + lane15 * 128 + sw0);
#pragma unroll
    for (int m = 0; m < 8; ++m)
      a0[m] = *(const short8*)(cb + wr * 16384 + m * 2048 + lane15 * 128 + sw0);
    __builtin_amdgcn_s_setprio(1);
#pragma unroll
    for (int m = 0; m < 8; ++m)
#pragma unroll
      for (int w = 0; w < NW; ++w)
#pragma unroll
        for (int n = 0; n < 2; ++n)
          acc[m][w][n] = __builtin_amdgcn_mfma_f32_16x16x32_bf16(a0[m], b0[w][n], acc[m][w][n], 0, 0, 0);
    __builtin_amdgcn_s_setprio(0);
#pragma unroll
    for (int w = 0; w < NW; ++w)
#pragma unroll
      for (int n = 0; n < 2; ++n)
        b1[w][n] = *(const short8*)(cb + ABYTES + w * 16384 + wc * 4096 + n * 2048 + lane15 * 128 + sw1);
#pragma unroll
    for (int m = 0; m < 8; ++m)
      a1[m] = *(const short8*)(cb + wr * 16384 + m * 2048 + lane15 * 128 + sw1);
    // all ds_reads of this buffer issued -> safe to overwrite after barrier
    __builtin_amdgcn_sched_barrier(0);
    __builtin_amdgcn_s_barrier();
    __builtin_amdgcn_sched_barrier(0);
    if (ktl + 2 < KTS) STAGE(kt0 + ktl + 2, ktl & 1);
    __builtin_amdgcn_s_setprio(1);
#pragma unroll
    for (int m = 0; m < 8; ++m)
#pragma unroll
      for (int w = 0; w < NW; ++w)
#pragma unroll
        for (int n = 0; n < 2; ++n)
          acc[m][w][n] = __builtin_amdgcn_mfma_f32_16x16x32_bf16(a1[m], b1[w][n], acc[m][w][n], 0, 0, 0);
    __builtin_amdgcn_s_setprio(0);
    if (ktl + 2 < KTS) waitv<CPW>();
    else if (ktl + 1 < KTS) waitv<0>();
    __builtin_amdgcn_sched_barrier(0);
    if (ktl + 1 < KTS) __builtin_amdgcn_s_barrier();
    __builtin_amdgcn_sched_barrier(0);
  }

  // ---- epilogue ----
  if constexpr (MODE == 1) {
    unsigned short* H = (unsigned short*)OUT + (size_t)e * CAP * NOUT;
#pragma unroll
    for (int m = 0; m < 8; ++m) {
#pragma unroll
      for (int n = 0; n < 2; ++n) {
        int row0 = bm * 256 + wr * 128 + m * 16 + lhi * 4;
        int col = bn * 128 + wc * 32 + n * 16 + lane15;
#pragma unroll
        for (int j = 0; j < 4; ++j) {
          float g1 = acc[m][0][n][j];
          float g3 = acc[m][1][n][j];
          float hv = g1 / (1.0f + __expf(-g1)) * g3;
          H[(size_t)(row0 + j) * NOUT + col] = f2bf(hv);
        }
      }
    }
  } else {
    // ungated split-K partial: one writer per (sk, e, row, col)
    float* P = (float*)OUT + (size_t)sk * 8 * CAP * NOUT + (size_t)e * CAP * NOUT;
#pragma unroll
    for (int m = 0; m < 8; ++m) {
#pragma unroll
      for (int w = 0; w < NW; ++w) {
#pragma unroll
        for (int n = 0; n < 2; ++n) {
          int row0 = bm * 256 + wr * 128 + m * 16 + lhi * 4;
          int col = bn * BNCOL + w * 128 + wc * 32 + n * 16 + lane15;
#pragma unroll
          for (int j = 0; j < 4; ++j)
            P[(size_t)(row0 + j) * NOUT + col] = acc[m][w][n][j];
        }
      }
    }
  }
}

// ---------------- combine: out[t] = sum_k g_k * (P0[e_k,s_k] + P1[e_k,s_k]) ----------------
__global__ void combine_kernel(const float* __restrict__ ob, const int* __restrict__ topi,
                               const float* __restrict__ gall, const int* __restrict__ slot,
                               float* __restrict__ out) {
  int t = blockIdx.x;
  int d = threadIdx.x * 4;
  const size_t HALF = (size_t)8 * CAP * D_MODEL;
  float4 r = make_float4(0.f, 0.f, 0.f, 0.f);
#pragma unroll
  for (int k = 0; k < 2; ++k) {
    int s = slot[t * 2 + k];
    if (s >= 0) {
      int e = topi[t * 2 + k];
      float g = gall[t * 2 + k];
      size_t base = ((size_t)e * CAP + s) * D_MODEL + d;
      float4 a = *(const float4*)(ob + base);
      float4 b = *(const float4*)(ob + HALF + base);
      r.x += g * (a.x + b.x); r.y += g * (a.y + b.y);
      r.z += g * (a.z + b.z); r.w += g * (a.w + b.w);
    }
  }
  *(float4*)(out + (size_t)t * D_MODEL + d) = r;
}

extern "C" void kernel_launch(void* const* d_in, const int* in_sizes, int n_in,
                              void* d_out, int out_size, void* d_ws, size_t ws_size,
                              hipStream_t stream) {
  const float* x     = (const float*)d_in[0];
  const float* noise = (const float*)d_in[1];
  const float* rw    = (const float*)d_in[2];
  const float* rb    = (const float*)d_in[3];
  const float* nw    = (const float*)d_in[4];
  const float* nb    = (const float*)d_in[5];
  const float* w1    = (const float*)d_in[6];
  const float* w3    = (const float*)d_in[7];
  const float* w2    = (const float*)d_in[8];
  float* out = (float*)d_out;

  char* ws = (char*)d_ws;
  size_t off = 0;
  auto alloc = [&](size_t bytes) -> void* {
    void* p = ws + off;
    off += (bytes + 255) & ~(size_t)255;
    return p;
  };
  const size_t WELEM = (size_t)8 * HIDDEN * D_MODEL;          // 23,068,672
  unsigned short* wb = (unsigned short*)alloc(3 * WELEM * 2); // wb1|wb3|wb2 contiguous
  unsigned short* xb = (unsigned short*)alloc((size_t)8 * CAP * D_MODEL * 2);
  unsigned short* h  = (unsigned short*)alloc((size_t)8 * CAP * HIDDEN * 2);
  float*          ob = (float*)alloc((size_t)2 * 8 * CAP * D_MODEL * 4);  // 2 split-K partials
  int*   topi  = (int*)alloc(N_TOK * 2 * 4);
  float* gall  = (float*)alloc(N_TOK * 2 * 4);
  int*   slot  = (int*)alloc(N_TOK * 2 * 4);
  int*   tokl  = (int*)alloc(8 * CAP * 4);
  (void)ws_size; (void)in_sizes; (void)n_in; (void)out_size;

  unsigned short* wb1 = wb;
  unsigned short* wb3 = wb + WELEM;
  unsigned short* wb2 = wb + 2 * WELEM;

  // prep: weight cvt (67584 blocks, head) + router (1024 blocks, tail), one dispatch
  prep_kernel<<<CVT_BLOCKS + 1024, 256, 0, stream>>>(
      x, noise, rw, rb, nw, nb, w1, w3, w2, wb, topi, gall, slot);

  scan_kernel<<<8, 1024, 0, stream>>>(topi, slot, tokl);
  gather_kernel<<<8 * CAP, 256, 0, stream>>>(x, tokl, xb);

  // FUSE GEMM12 + silu: h = silu(xb@w1^T) * (xb@w3^T), bf16. 8e*4bm*22bn = 704 wgs.
  gemm_moe<HIDDEN, D_MODEL, 2, 1><<<dim3(704), 512, 0, stream>>>(xb, wb1, wb3, (void*)h);

  // PART GEMM3: ob[sk] = h @ w2^T partials. BN=256, split-K2: 256 wgs.
  gemm_moe<D_MODEL, HIDDEN, 2, 2><<<dim3(256), 512, 0, stream>>>(
      h, wb2, wb2 + (size_t)128 * HIDDEN, (void*)ob);

  // combine partials with gates; plain stores (no memset needed)
  combine_kernel<<<N_TOK, 256, 0, stream>>>(ob, topi, gall, slot, out);
}